// Round 1
// baseline (704.632 us; speedup 1.0000x reference)
//
#include <hip/hip_runtime.h>

// out[i][j] = (sd[i][j] < 5 ? 1 : 0)
//           * (lbl[i]==lbl[j] ? 1.0 : 0.1)
//           * exp(-(sd^2 + dtw^2))        // fused: exp(-sd^2)*exp(-dtw^2)
//
// N = 8192, float32. adj_mx (d_in[0]) is unused by the reference -> never read.
//
// V2 vs V1: batch-of-4 per thread with all 8 float4 loads issued before any
// use (V1 had VGPR_Count=12 -> <=2 loads in flight per wave -> latency-bound
// at 2.8 TB/s HBM). Plus scalar (readfirstlane) row-label load and
// non-temporal stores to keep the write stream out of L3's way.

#define N_DIM 8192
#define DTW_DELTA 5.0f
#define EPS_CLU 0.1f

typedef float f4  __attribute__((ext_vector_type(4)));
typedef int   i4v __attribute__((ext_vector_type(4)));

__device__ __forceinline__ f4 calc(f4 s, f4 d, int li, i4v lj)
{
    f4 o;
#pragma unroll
    for (int k = 0; k < 4; ++k) {
        float g = __expf(-(s[k] * s[k] + d[k] * d[k]));
        float v = (li == lj[k]) ? g : EPS_CLU * g;
        o[k] = (s[k] < DTW_DELTA) ? v : 0.0f;
    }
    return o;
}

__global__ __launch_bounds__(256) void dtw_mask_kernel(
    const f4*  __restrict__ sd4,
    const f4*  __restrict__ dtw4,
    const int* __restrict__ lbl,
    f4*        __restrict__ out4)
{
    const long long nvec   = (long long)N_DIM * N_DIM / 4;      // 16.7M float4
    const long long stride = (long long)gridDim.x * blockDim.x; // float4 units
    long long i0 = (long long)blockIdx.x * blockDim.x + threadIdx.x;

    const i4v* __restrict__ lbl4 = (const i4v*)lbl;

    // Index math: element e = i*4; row = e>>13 = i>>11 (wave-uniform: a wave
    // covers 256 aligned elements, 8192%256==0 so it never crosses a row);
    // col-of-.x/4 = i & 2047.
    long long i1 = i0 + stride, i2 = i1 + stride, i3 = i2 + stride;

    if (i3 < nvec) {
        // ---- issue all 8 HBM loads before any use (4x MLP) ----
        f4 s0 = sd4[i0],  s1 = sd4[i1],  s2 = sd4[i2],  s3 = sd4[i3];
        f4 d0 = dtw4[i0], d1 = dtw4[i1], d2 = dtw4[i2], d3 = dtw4[i3];

        // cache-resident label reads (32 KB total, L1/L2 hits)
        i4v lj0 = lbl4[i0 & (N_DIM / 4 - 1)];
        i4v lj1 = lbl4[i1 & (N_DIM / 4 - 1)];
        i4v lj2 = lbl4[i2 & (N_DIM / 4 - 1)];
        i4v lj3 = lbl4[i3 & (N_DIM / 4 - 1)];
        int li0 = lbl[__builtin_amdgcn_readfirstlane((int)(i0 >> 11))];
        int li1 = lbl[__builtin_amdgcn_readfirstlane((int)(i1 >> 11))];
        int li2 = lbl[__builtin_amdgcn_readfirstlane((int)(i2 >> 11))];
        int li3 = lbl[__builtin_amdgcn_readfirstlane((int)(i3 >> 11))];

        f4 o0 = calc(s0, d0, li0, lj0);
        f4 o1 = calc(s1, d1, li1, lj1);
        f4 o2 = calc(s2, d2, li2, lj2);
        f4 o3 = calc(s3, d3, li3, lj3);

        __builtin_nontemporal_store(o0, &out4[i0]);
        __builtin_nontemporal_store(o1, &out4[i1]);
        __builtin_nontemporal_store(o2, &out4[i2]);
        __builtin_nontemporal_store(o3, &out4[i3]);

        i0 = i3 + stride;   // past our batch; tail loop below is dead when
                            // the grid divides nvec exactly (it does: 16384)
    }

    // safety tail (never executes with the launcher's exact grid sizing)
    for (; i0 < nvec; i0 += stride) {
        f4  s  = sd4[i0];
        f4  d  = dtw4[i0];
        i4v lj = lbl4[i0 & (N_DIM / 4 - 1)];
        int li = lbl[__builtin_amdgcn_readfirstlane((int)(i0 >> 11))];
        __builtin_nontemporal_store(calc(s, d, li, lj), &out4[i0]);
    }
}

extern "C" void kernel_launch(void* const* d_in, const int* in_sizes, int n_in,
                              void* d_out, int out_size, void* d_ws, size_t ws_size,
                              hipStream_t stream)
{
    // setup_inputs order: adj_mx, sd_mx, dtw_matrix, cluster_labels
    const f4*  sd  = (const f4*)d_in[1];
    const f4*  dtw = (const f4*)d_in[2];
    const int* lbl = (const int*)d_in[3];
    f4* out = (f4*)d_out;

    const long long nvec = (long long)N_DIM * N_DIM / 4;  // 16,777,216
    const int block = 256;
    // exactly 4 float4s per thread: 16384 blocks x 256 threads x 4
    long long grid = nvec / ((long long)block * 4);        // = 16384
    if (grid * block * 4 < nvec) ++grid;                   // tail safety
    dtw_mask_kernel<<<(int)grid, block, 0, stream>>>(sd, dtw, lbl, out);
}

// Round 2
// 670.897 us; speedup vs baseline: 1.0503x; 1.0503x over previous
//
#include <hip/hip_runtime.h>

// out[i][j] = (sd[i][j] < 5 ? 1 : 0)
//           * (lbl[i]==lbl[j] ? 1.0 : 0.1)
//           * exp(-(sd^2 + dtw^2))        // fused: exp(-sd^2)*exp(-dtw^2)
//
// N = 8192, float32. adj_mx (d_in[0]) is unused by the reference -> never read.
//
// V3: batch-of-4 loads per thread for MLP (V1's VGPR=12 loop had only 2 loads
// in flight -> 2.8 TB/s latency-bound), but with BLOCK-CONTIGUOUS addressing:
// each block owns 1024 consecutive float4s (items at blockBase + k*256 + tid).
// All 8 loads of a thread stay in a 16 KiB window per array (DRAM row
// locality), every block lies entirely inside one matrix row (1024 | 2048)
// so lbl[row] is a block-uniform broadcast. Plain stores (V2's non-temporal
// stores bypassed L2 write-combining and regressed 190->225 us).

#define N_DIM 8192
#define DTW_DELTA 5.0f
#define EPS_CLU 0.1f

typedef float f4  __attribute__((ext_vector_type(4)));
typedef int   i4v __attribute__((ext_vector_type(4)));

__device__ __forceinline__ f4 calc(f4 s, f4 d, int li, i4v lj)
{
    f4 o;
#pragma unroll
    for (int k = 0; k < 4; ++k) {
        float g = __expf(-(s[k] * s[k] + d[k] * d[k]));
        float v = (li == lj[k]) ? g : EPS_CLU * g;
        o[k] = (s[k] < DTW_DELTA) ? v : 0.0f;
    }
    return o;
}

__global__ __launch_bounds__(256) void dtw_mask_kernel(
    const f4*  __restrict__ sd4,
    const f4*  __restrict__ dtw4,
    const int* __restrict__ lbl,
    f4*        __restrict__ out4)
{
    // Each block: 1024 consecutive float4s. 16384 blocks x 1024 = 16,777,216
    // float4s = 8192*8192 floats exactly. No tail.
    const long long base = (long long)blockIdx.x * 1024 + threadIdx.x;
    const long long i0 = base;
    const long long i1 = base + 256;
    const long long i2 = base + 512;
    const long long i3 = base + 768;

    const i4v* __restrict__ lbl4 = (const i4v*)lbl;

    // ---- issue all 8 big loads before any use (4x MLP vs V1) ----
    f4 s0 = sd4[i0],  s1 = sd4[i1],  s2 = sd4[i2],  s3 = sd4[i3];
    f4 d0 = dtw4[i0], d1 = dtw4[i1], d2 = dtw4[i2], d3 = dtw4[i3];

    // row = (float4 idx) >> 11; block spans 1024 float4s and 1024 | 2048,
    // so the row is uniform across the whole block -> broadcast L1 hit.
    const int li = lbl[(int)(base >> 11)];

    // col labels: 32 KB array, L1/L2 resident
    const int m = N_DIM / 4 - 1;
    i4v lj0 = lbl4[(int)(i0 & m)];
    i4v lj1 = lbl4[(int)(i1 & m)];
    i4v lj2 = lbl4[(int)(i2 & m)];
    i4v lj3 = lbl4[(int)(i3 & m)];

    out4[i0] = calc(s0, d0, li, lj0);
    out4[i1] = calc(s1, d1, li, lj1);
    out4[i2] = calc(s2, d2, li, lj2);
    out4[i3] = calc(s3, d3, li, lj3);
}

extern "C" void kernel_launch(void* const* d_in, const int* in_sizes, int n_in,
                              void* d_out, int out_size, void* d_ws, size_t ws_size,
                              hipStream_t stream)
{
    // setup_inputs order: adj_mx, sd_mx, dtw_matrix, cluster_labels
    const f4*  sd  = (const f4*)d_in[1];
    const f4*  dtw = (const f4*)d_in[2];
    const int* lbl = (const int*)d_in[3];
    f4* out = (f4*)d_out;

    const long long nvec = (long long)N_DIM * N_DIM / 4;   // 16,777,216
    const int block = 256;
    const int items_per_block = block * 4;                 // 1024 float4s
    int grid = (int)((nvec + items_per_block - 1) / items_per_block); // 16384
    dtw_mask_kernel<<<grid, block, 0, stream>>>(sd, dtw, lbl, out);
}